// Round 9
// baseline (466.999 us; speedup 1.0000x reference)
//
#include <hip/hip_runtime.h>
#include <hip/hip_bf16.h>
#include <math.h>

#define D_MODEL 256
#define D_INNER 512
#define D_STATE 16
#define D_CONV 4
#define DT_RANK 16
#define N_LAYERS 4
#define CITY 300
#define BATCH 32
#define SEQ 300
#define NTOK (BATCH * SEQ)   // 9600
#define NSEG 15
#define SEGLEN (SEQ / NSEG)  // 20

typedef __attribute__((ext_vector_type(8))) short short8v;
typedef __attribute__((ext_vector_type(4))) float f32x4;
typedef __attribute__((ext_vector_type(2))) float f32x2;

#define L2E_F 1.44269504088896340736f
#define LN2_F 0.69314718055994530942f

__device__ __forceinline__ float fexp2(float x) { return __builtin_amdgcn_exp2f(x); }
__device__ __forceinline__ float flog2(float x) { return __builtin_amdgcn_logf(x); }

__device__ __forceinline__ float fast_sig(float x) {
    return __builtin_amdgcn_rcpf(1.f + fexp2(-x * L2E_F));
}

__device__ __forceinline__ float softplus_f(float x) {
    float t = fexp2(-fabsf(x) * L2E_F);
    return fmaxf(x, 0.f) + flog2(1.f + t) * LN2_F;
}

__device__ __forceinline__ unsigned short f2b(float a) {
    __hip_bfloat16 h = __float2bfloat16(a);
    return *reinterpret_cast<unsigned short*>(&h);
}

__device__ __forceinline__ float b2f(unsigned short u) {
    unsigned int x = ((unsigned int)u) << 16;
    return __uint_as_float(x);
}

// packed dt-projection: sum_{r<16} rb[r]*dW[r] + dtb   (8 x v_pk_fma_f32)
__device__ __forceinline__ float dtproj8(const float* rb, const f32x2* w2, float dtbv) {
    const f32x2* r2 = (const f32x2*)rb;
    f32x2 a0, a1, a2, a3;
    a0.x = dtbv; a0.y = 0.f;
    a1.x = 0.f; a1.y = 0.f;
    a2 = a1; a3 = a1;
    a0 = __builtin_elementwise_fma(r2[0], w2[0], a0);
    a1 = __builtin_elementwise_fma(r2[1], w2[1], a1);
    a2 = __builtin_elementwise_fma(r2[2], w2[2], a2);
    a3 = __builtin_elementwise_fma(r2[3], w2[3], a3);
    a0 = __builtin_elementwise_fma(r2[4], w2[4], a0);
    a1 = __builtin_elementwise_fma(r2[5], w2[5], a1);
    a2 = __builtin_elementwise_fma(r2[6], w2[6], a2);
    a3 = __builtin_elementwise_fma(r2[7], w2[7], a3);
    f32x2 s = (a0 + a1) + (a2 + a3);
    return s.x + s.y;
}

// ---------------- all weight conversions, vectorized ----------------
__global__ void cvt4_kernel(const float* __restrict__ s0, unsigned short* __restrict__ d0, int n0,
                            const float* __restrict__ s1, unsigned short* __restrict__ d1, int n1,
                            const float* __restrict__ s2, unsigned short* __restrict__ d2, int n2,
                            const float* __restrict__ s3, unsigned short* __restrict__ d3, int n3) {
    int stride = gridDim.x * blockDim.x;
    int tid = blockIdx.x * blockDim.x + threadIdx.x;
    for (int i = tid; i < n0 / 4; i += stride) {
        float4 v = ((const float4*)s0)[i];
        ushort4 o; o.x = f2b(v.x); o.y = f2b(v.y); o.z = f2b(v.z); o.w = f2b(v.w);
        ((ushort4*)d0)[i] = o;
    }
    for (int i = tid; i < n1 / 4; i += stride) {
        float4 v = ((const float4*)s1)[i];
        ushort4 o; o.x = f2b(v.x); o.y = f2b(v.y); o.z = f2b(v.z); o.w = f2b(v.w);
        ((ushort4*)d1)[i] = o;
    }
    for (int i = tid; i < n2 / 4; i += stride) {
        float4 v = ((const float4*)s2)[i];
        ushort4 o; o.x = f2b(v.x); o.y = f2b(v.y); o.z = f2b(v.z); o.w = f2b(v.w);
        ((ushort4*)d2)[i] = o;
    }
    for (int i = tid; i < n3 / 4; i += stride) {
        float4 v = ((const float4*)s3)[i];
        ushort4 o; o.x = f2b(v.x); o.y = f2b(v.y); o.z = f2b(v.z); o.w = f2b(v.w);
        ((ushort4*)d3)[i] = o;
    }
}

// ---------------- embedding + layer-0 residual init + LN (fused) ----------------
__global__ void embed_ln_kernel(const float* __restrict__ coords,
                                const float* __restrict__ eW,
                                const float* __restrict__ eb,
                                const float* __restrict__ w,
                                const float* __restrict__ b,
                                float* __restrict__ resid,
                                unsigned short* __restrict__ hb) {
    int t = blockIdx.x, d = threadIdx.x;
    float c0 = coords[t * 2 + 0];
    float c1 = coords[t * 2 + 1];
    float r = c0 * eW[d * 2 + 0] + c1 * eW[d * 2 + 1] + eb[d];
    resid[t * D_MODEL + d] = r;
    float s1 = r, s2 = r * r;
#pragma unroll
    for (int m = 1; m < 64; m <<= 1) {
        s1 += __shfl_xor(s1, m);
        s2 += __shfl_xor(s2, m);
    }
    __shared__ float p1[4], p2[4];
    if ((d & 63) == 0) { p1[d >> 6] = s1; p2[d >> 6] = s2; }
    __syncthreads();
    s1 = (p1[0] + p1[1]) + (p1[2] + p1[3]);
    s2 = (p2[0] + p2[1]) + (p2[2] + p2[3]);
    float mean = s1 * (1.f / D_MODEL);
    float var = s2 * (1.f / D_MODEL) - mean * mean;
    hb[t * D_MODEL + d] = f2b((r - mean) * rsqrtf(var + 1e-5f) * w[d] + b[d]);
}

// ------------- bf16-in MFMA GEMM: C[t,n] = sum_k A[t,k] * W[n,k] -------------
template <int BM, int BN, bool GN, bool OB>
__global__ __launch_bounds__(256, 2) void gemm_mfma(const unsigned short* __restrict__ A,
                                                    const unsigned short* __restrict__ W,
                                                    void* __restrict__ C, int N, int K) {
    constexpr int TI = BM / 32;
    constexpr int TJ = BN / 32;
    __shared__ short Als[BM * 32];
    __shared__ short Bls[BN * 32];
    const int tid = threadIdx.x;
    const int lane = tid & 63, wid = tid >> 6;
    const int wr = wid >> 1, wc = wid & 1;
    const int t0 = blockIdx.x * BM, n0 = blockIdx.y * BN;
    f32x4 acc[TI][TJ] = {};

    for (int k0 = 0; k0 < K; k0 += 32) {
#pragma unroll
        for (int it = 0; it < BM / 64; ++it) {
            int s = tid + it * 256;
            int m = s >> 2, q = s & 3;
            uint4 p = *(const uint4*)(A + (size_t)(t0 + m) * K + k0 + q * 8);
            *(uint4*)&Als[(((m >> 4) * 4 + q) * 16 + (m & 15)) * 8] = p;
        }
#pragma unroll
        for (int it = 0; it < BN / 64; ++it) {
            int s = tid + it * 256;
            int n = s >> 2, q = s & 3;
            int nrow = n0 + n;
            uint4 p = make_uint4(0u, 0u, 0u, 0u);
            if (!GN || nrow < N)
                p = *(const uint4*)(W + (size_t)nrow * K + k0 + q * 8);
            *(uint4*)&Bls[(((n >> 4) * 4 + q) * 16 + (n & 15)) * 8] = p;
        }
        __syncthreads();
        short8v af[TI], bf[TJ];
#pragma unroll
        for (int i = 0; i < TI; i++)
            af[i] = *(const short8v*)&Als[(wr * TI + i) * 512 + lane * 8];
#pragma unroll
        for (int j = 0; j < TJ; j++)
            bf[j] = *(const short8v*)&Bls[(wc * TJ + j) * 512 + lane * 8];
#pragma unroll
        for (int i = 0; i < TI; i++)
#pragma unroll
            for (int j = 0; j < TJ; j++)
                acc[i][j] = __builtin_amdgcn_mfma_f32_16x16x32_bf16(
                    af[i], bf[j], acc[i][j], 0, 0, 0);
        __syncthreads();
    }
    const int rq = lane >> 4, cn = lane & 15;
#pragma unroll
    for (int i = 0; i < TI; i++) {
        int trow = t0 + wr * (BM / 2) + i * 16 + rq * 4;
#pragma unroll
        for (int j = 0; j < TJ; j++) {
            int ncol = n0 + wc * (BN / 2) + j * 16 + cn;
            if (!GN || ncol < N) {
#pragma unroll
                for (int reg = 0; reg < 4; reg++) {
                    if constexpr (OB)
                        ((unsigned short*)C)[(size_t)(trow + reg) * N + ncol] =
                            f2b(acc[i][j][reg]);
                    else
                        ((float*)C)[(size_t)(trow + reg) * N + ncol] = acc[i][j][reg];
                }
            }
        }
    }
}

// ===== fused causal conv(k=4)+SiLU + xproj GEMM; also emits xcb (bf16 conv out) =====
__global__ __launch_bounds__(256, 2) void xproj_conv(
    const unsigned short* __restrict__ xzb,
    const float* __restrict__ cW, const float* __restrict__ cb,
    const unsigned short* __restrict__ W,
    unsigned short* __restrict__ xcb, float* __restrict__ dblo) {
    constexpr int TI = 2, TJ = 2;   // BM=64, BN=64
    const int K = D_INNER, N = 48;
    __shared__ short Als[64 * 32];
    __shared__ short Bls[64 * 32];
    __shared__ float cwL[D_INNER * 4];   // 8 KB: [ch*4 + tap]
    __shared__ float cbL[D_INNER];       // 2 KB
    const int tid = threadIdx.x;
    const int lane = tid & 63, wid = tid >> 6;
    const int wr = wid >> 1, wc = wid & 1;
    const int t0 = blockIdx.x * 64;

    for (int i = tid; i < D_INNER; i += 256) {
        ((float4*)cwL)[i] = ((const float4*)cW)[i];
        cbL[i] = cb[i];
    }
    __syncthreads();

    f32x4 acc[TI][TJ] = {};
    const int m = tid >> 2, q = tid & 3;
    const int t = t0 + m;
    const int l = t % SEQ;

    for (int k0 = 0; k0 < K; k0 += 32) {
        {
            const int ch0 = k0 + q * 8;
            const unsigned short* xr = xzb + (size_t)t * 1024 + ch0;
            uint4 u0 = make_uint4(0u, 0u, 0u, 0u), u1 = u0, u2 = u0, u3;
            if (l >= 3) u0 = *(const uint4*)(xr - 3 * 1024);
            if (l >= 2) u1 = *(const uint4*)(xr - 2 * 1024);
            if (l >= 1) u2 = *(const uint4*)(xr - 1 * 1024);
            u3 = *(const uint4*)xr;
            unsigned int ow0, ow1, ow2, ow3;
#pragma unroll
            for (int c2 = 0; c2 < 4; c2++) {
                unsigned int w0 = (c2 == 0) ? u0.x : (c2 == 1) ? u0.y : (c2 == 2) ? u0.z : u0.w;
                unsigned int w1 = (c2 == 0) ? u1.x : (c2 == 1) ? u1.y : (c2 == 2) ? u1.z : u1.w;
                unsigned int w2 = (c2 == 0) ? u2.x : (c2 == 1) ? u2.y : (c2 == 2) ? u2.z : u2.w;
                unsigned int w3 = (c2 == 0) ? u3.x : (c2 == 1) ? u3.y : (c2 == 2) ? u3.z : u3.w;
                int chA = ch0 + c2 * 2, chB = chA + 1;
                float4 wvA = *(const float4*)&cwL[chA * 4];
                float4 wvB = *(const float4*)&cwL[chB * 4];
                float aA = cbL[chA], aB = cbL[chB];
                aA = fmaf(b2f((unsigned short)(w0 & 0xffffu)), wvA.x, aA);
                aB = fmaf(b2f((unsigned short)(w0 >> 16)), wvB.x, aB);
                aA = fmaf(b2f((unsigned short)(w1 & 0xffffu)), wvA.y, aA);
                aB = fmaf(b2f((unsigned short)(w1 >> 16)), wvB.y, aB);
                aA = fmaf(b2f((unsigned short)(w2 & 0xffffu)), wvA.z, aA);
                aB = fmaf(b2f((unsigned short)(w2 >> 16)), wvB.z, aB);
                aA = fmaf(b2f((unsigned short)(w3 & 0xffffu)), wvA.w, aA);
                aB = fmaf(b2f((unsigned short)(w3 >> 16)), wvB.w, aB);
                aA = aA * fast_sig(aA);
                aB = aB * fast_sig(aB);
                unsigned int pk = (unsigned int)f2b(aA) | ((unsigned int)f2b(aB) << 16);
                if (c2 == 0) ow0 = pk; else if (c2 == 1) ow1 = pk; else if (c2 == 2) ow2 = pk; else ow3 = pk;
            }
            uint4 pk4 = make_uint4(ow0, ow1, ow2, ow3);
            *(uint4*)&Als[(((m >> 4) * 4 + q) * 16 + (m & 15)) * 8] = pk4;
            *(uint4*)(xcb + (size_t)t * 512 + ch0) = pk4;
        }
        {
            int n = tid >> 2;
            uint4 p = make_uint4(0u, 0u, 0u, 0u);
            if (n < N) p = *(const uint4*)(W + (size_t)n * K + k0 + q * 8);
            *(uint4*)&Bls[(((n >> 4) * 4 + q) * 16 + (n & 15)) * 8] = p;
        }
        __syncthreads();
        short8v af[TI], bf[TJ];
#pragma unroll
        for (int i = 0; i < TI; i++)
            af[i] = *(const short8v*)&Als[(wr * TI + i) * 512 + lane * 8];
#pragma unroll
        for (int j = 0; j < TJ; j++)
            bf[j] = *(const short8v*)&Bls[(wc * TJ + j) * 512 + lane * 8];
#pragma unroll
        for (int i = 0; i < TI; i++)
#pragma unroll
            for (int j = 0; j < TJ; j++)
                acc[i][j] = __builtin_amdgcn_mfma_f32_16x16x32_bf16(
                    af[i], bf[j], acc[i][j], 0, 0, 0);
        __syncthreads();
    }
    const int rq = lane >> 4, cn = lane & 15;
#pragma unroll
    for (int i = 0; i < TI; i++) {
        int trow = t0 + (wr * TI + i) * 16 + rq * 4;
#pragma unroll
        for (int j = 0; j < TJ; j++) {
            int ncol = wc * 32 + j * 16 + cn;
            if (ncol < N) {
#pragma unroll
                for (int reg = 0; reg < 4; reg++)
                    dblo[(size_t)(trow + reg) * N + ncol] = acc[i][j][reg];
            }
        }
    }
}

// ------------- out_proj GEMM + residual add + LN/RMS fused epilogue -------------
// HEAD variant (implies RMS): normalized rows staged in LDS, head GEMM -> out; no hb write.
template <bool RMS, bool HEAD>
__global__ __launch_bounds__(256, 2) void gemm_out_ln(const unsigned short* __restrict__ A,
                                                      const unsigned short* __restrict__ W,
                                                      float* __restrict__ resid,
                                                      const float* __restrict__ w,
                                                      const float* __restrict__ b,
                                                      unsigned short* __restrict__ hb,
                                                      const unsigned short* __restrict__ hW,
                                                      float* __restrict__ outp) {
    constexpr int TI = 2, TJ = 8;
    const int K = D_INNER;
    __shared__ short Als[64 * 32];
    __shared__ short Bls[256 * 32];
    __shared__ float rs1[2][64], rs2[2][64];
    __shared__ short hN[HEAD ? 64 * 256 : 1];   // 32 KB slab-swizzled normalized rows
    const int tid = threadIdx.x;
    const int lane = tid & 63, wid = tid >> 6;
    const int wr = wid >> 1, wc = wid & 1;
    const int t0 = blockIdx.x * 64;
    f32x4 acc[TI][TJ] = {};

    for (int k0 = 0; k0 < K; k0 += 32) {
        {
            int s = tid;
            int m = s >> 2, q = s & 3;
            uint4 p = *(const uint4*)(A + (size_t)(t0 + m) * K + k0 + q * 8);
            *(uint4*)&Als[(((m >> 4) * 4 + q) * 16 + (m & 15)) * 8] = p;
        }
#pragma unroll
        for (int it = 0; it < 4; ++it) {
            int s = tid + it * 256;
            int n = s >> 2, q = s & 3;
            uint4 p = *(const uint4*)(W + (size_t)n * K + k0 + q * 8);
            *(uint4*)&Bls[(((n >> 4) * 4 + q) * 16 + (n & 15)) * 8] = p;
        }
        __syncthreads();
        short8v af[TI], bf[TJ];
#pragma unroll
        for (int i = 0; i < TI; i++)
            af[i] = *(const short8v*)&Als[(wr * TI + i) * 512 + lane * 8];
#pragma unroll
        for (int j = 0; j < TJ; j++)
            bf[j] = *(const short8v*)&Bls[(wc * TJ + j) * 512 + lane * 8];
#pragma unroll
        for (int i = 0; i < TI; i++)
#pragma unroll
            for (int j = 0; j < TJ; j++)
                acc[i][j] = __builtin_amdgcn_mfma_f32_16x16x32_bf16(
                    af[i], bf[j], acc[i][j], 0, 0, 0);
        __syncthreads();
    }
    const int rq = lane >> 4, cn = lane & 15;
    float s1p[TI][4], s2p[TI][4];
#pragma unroll
    for (int i = 0; i < TI; i++) {
        int trow = t0 + wr * 32 + i * 16 + rq * 4;
#pragma unroll
        for (int reg = 0; reg < 4; reg++) { s1p[i][reg] = 0.f; s2p[i][reg] = 0.f; }
#pragma unroll
        for (int j = 0; j < TJ; j++) {
            int c = wc * 128 + j * 16 + cn;
#pragma unroll
            for (int reg = 0; reg < 4; reg++) {
                float rv = acc[i][j][reg] + resid[(size_t)(trow + reg) * D_MODEL + c];
                acc[i][j][reg] = rv;
                s1p[i][reg] += rv;
                s2p[i][reg] = fmaf(rv, rv, s2p[i][reg]);
            }
        }
    }
#pragma unroll
    for (int m = 1; m < 16; m <<= 1) {
#pragma unroll
        for (int i = 0; i < TI; i++)
#pragma unroll
            for (int reg = 0; reg < 4; reg++) {
                s1p[i][reg] += __shfl_xor(s1p[i][reg], m);
                s2p[i][reg] += __shfl_xor(s2p[i][reg], m);
            }
    }
    if (cn == 0) {
#pragma unroll
        for (int i = 0; i < TI; i++)
#pragma unroll
            for (int reg = 0; reg < 4; reg++) {
                int rloc = wr * 32 + i * 16 + rq * 4 + reg;
                rs1[wc][rloc] = s1p[i][reg];
                rs2[wc][rloc] = s2p[i][reg];
            }
    }
    __syncthreads();
    float wv[TJ], bv[TJ];
#pragma unroll
    for (int j = 0; j < TJ; j++) {
        int c = wc * 128 + j * 16 + cn;
        wv[j] = w[c];
        bv[j] = b[c];
    }
#pragma unroll
    for (int i = 0; i < TI; i++) {
        int trow = t0 + wr * 32 + i * 16 + rq * 4;
#pragma unroll
        for (int reg = 0; reg < 4; reg++) {
            int rloc = wr * 32 + i * 16 + rq * 4 + reg;
            float S1 = rs1[0][rloc] + rs1[1][rloc];
            float S2 = rs2[0][rloc] + rs2[1][rloc];
            float mean, rstd;
            if constexpr (RMS) {
                mean = 0.f;
                rstd = rsqrtf(S2 * (1.f / D_MODEL) + 1e-5f);
            } else {
                mean = S1 * (1.f / D_MODEL);
                float var = S2 * (1.f / D_MODEL) - mean * mean;
                rstd = rsqrtf(var + 1e-5f);
            }
#pragma unroll
            for (int j = 0; j < TJ; j++) {
                int c = wc * 128 + j * 16 + cn;
                float rv = acc[i][j][reg];
                unsigned short nv = f2b((rv - mean) * rstd * wv[j] + bv[j]);
                if constexpr (HEAD) {
                    int mrow = wr * 32 + i * 16 + rq * 4 + reg;
                    hN[(c >> 5) * 2048 + (((mrow >> 4) * 4 + ((c & 31) >> 3)) * 16 + (mrow & 15)) * 8 + (c & 7)] = (short)nv;
                } else {
                    hb[(size_t)(trow + reg) * D_MODEL + c] = nv;
                }
                if constexpr (!RMS)
                    resid[(size_t)(trow + reg) * D_MODEL + c] = rv;
            }
        }
    }
    if constexpr (HEAD) {
        __syncthreads();
        // head GEMM: out[t, n] = sum_k norm[t,k] * head_W[n,k]; N=300 in 5 chunks of 64
        for (int nch = 0; nch < 5; ++nch) {
            f32x4 acc2[2][2] = {};
            for (int k0 = 0; k0 < D_MODEL; k0 += 32) {
                int n = tid >> 2, q = tid & 3;
                int nrow = nch * 64 + n;
                uint4 p = make_uint4(0u, 0u, 0u, 0u);
                if (nrow < CITY) p = *(const uint4*)(hW + (size_t)nrow * D_MODEL + k0 + q * 8);
                *(uint4*)&Bls[(((n >> 4) * 4 + q) * 16 + (n & 15)) * 8] = p;
                __syncthreads();
                short8v af2[2], bf2[2];
#pragma unroll
                for (int i = 0; i < 2; i++)
                    af2[i] = *(const short8v*)&hN[(k0 >> 5) * 2048 + (wr * 2 + i) * 512 + lane * 8];
#pragma unroll
                for (int j = 0; j < 2; j++)
                    bf2[j] = *(const short8v*)&Bls[(wc * 2 + j) * 512 + lane * 8];
#pragma unroll
                for (int i = 0; i < 2; i++)
#pragma unroll
                    for (int j = 0; j < 2; j++)
                        acc2[i][j] = __builtin_amdgcn_mfma_f32_16x16x32_bf16(
                            af2[i], bf2[j], acc2[i][j], 0, 0, 0);
                __syncthreads();
            }
#pragma unroll
            for (int i = 0; i < 2; i++) {
                int trow = t0 + (wr * 2 + i) * 16 + rq * 4;
#pragma unroll
                for (int j = 0; j < 2; j++) {
                    int ncol = nch * 64 + wc * 32 + j * 16 + cn;
                    if (ncol < CITY) {
#pragma unroll
                        for (int reg = 0; reg < 4; reg++)
                            outp[(size_t)(trow + reg) * CITY + ncol] = acc2[i][j][reg];
                    }
                }
            }
        }
    }
}

// ========== block-local 3-phase scan; decay-only phase 3 (R2-verified algebra,
// R1-safe implementation: runtime loops, rolling buffers, global round-trip).
// Phase 1: full local scan from h=0, emits dtt AND wl = C·h_local + x*D_skip.
// Phase 3: hc *= exp2(dtt*A); y = wl + C·hc; gate; store. No x/B reload.
// NOTE: seg MUST be wave-uniform (readfirstlane) so row addrs scalarize to SGPRs.
__global__ __launch_bounds__(960) void scan_block(
    const unsigned short* __restrict__ xcb, const float* __restrict__ dbl,
    const unsigned short* __restrict__ xzb,
    const float* __restrict__ A_log, const float* __restrict__ Dskip,
    const float* __restrict__ dtW, const float* __restrict__ dtb,
    float* __restrict__ dts, float* __restrict__ wls,
    unsigned short* __restrict__ yb) {
    __shared__ float lh[NSEG * D_STATE * 64];
    __shared__ float lsd[NSEG * 64];
    const int b = blockIdx.x, dg = blockIdx.y;
    const int tid = threadIdx.x;
    const int lane = tid & 63;
    const int seg = __builtin_amdgcn_readfirstlane(tid >> 6);
    const int d = (dg << 6) + lane;
    f32x2 A2[8], w2[8];
#pragma unroll
    for (int s4 = 0; s4 < 4; s4++) {
        float4 v = *(const float4*)(A_log + (size_t)d * D_STATE + s4 * 4);
        f32x2 pa, pb;
        pa.x = -fexp2(v.x * L2E_F) * L2E_F;
        pa.y = -fexp2(v.y * L2E_F) * L2E_F;
        pb.x = -fexp2(v.z * L2E_F) * L2E_F;
        pb.y = -fexp2(v.w * L2E_F) * L2E_F;
        A2[s4 * 2 + 0] = pa;
        A2[s4 * 2 + 1] = pb;
        float4 w = *(const float4*)(dtW + (size_t)d * DT_RANK + s4 * 4);
        f32x2 qa, qb;
        qa.x = w.x; qa.y = w.y;
        qb.x = w.z; qb.y = w.w;
        w2[s4 * 2 + 0] = qa;
        w2[s4 * 2 + 1] = qb;
    }
    const float dtbv = dtb[d], dsk = Dskip[d];
    const size_t tb = (size_t)b * SEQ + (size_t)seg * SEGLEN;
    const float* __restrict__ dr = dbl + tb * 48;
    const unsigned short* __restrict__ xp = xcb + tb * 512 + d;
    const unsigned short* __restrict__ zp = xzb + tb * 1024 + 512 + d;
    float* __restrict__ dtp = dts + tb * 512 + d;
    float* __restrict__ wlp = wls + tb * 512 + d;
    unsigned short* __restrict__ yp = yb + tb * 512 + d;

    // ---------------- phase 1: local scan from h=0; emit dtt + wl ----------------
    {
        f32x2 h2[8];
#pragma unroll
        for (int i = 0; i < 8; i++) { h2[i].x = 0.f; h2[i].y = 0.f; }
        float sdt = 0.f;
        float dbA[48], dbB[48];
#pragma unroll
        for (int i = 0; i < 12; i++) ((float4*)dbA)[i] = ((const float4*)dr)[i];
        float xv = b2f(xp[0]);
        for (int l = 0; l < SEGLEN; l += 2) {
            const float4* nr1 = (const float4*)(dr + (size_t)(l + 1) * 48);
#pragma unroll
            for (int i = 0; i < 12; i++) ((float4*)dbB)[i] = nr1[i];
            float xv1 = b2f(xp[(size_t)(l + 1) * 512]);
            {
                float acc = dtproj8(dbA, w2, dtbv);
                float dtt = softplus_f(acc);
                dtp[(size_t)l * 512] = dtt;
                sdt += dtt;
                float dtx = dtt * xv;
                f32x2 dtt2, dtx2;
                dtt2.x = dtt; dtt2.y = dtt;
                dtx2.x = dtx; dtx2.y = dtx;
                const f32x2* B2 = (const f32x2*)(dbA + 16);
                const f32x2* C2 = (const f32x2*)(dbA + 32);
                f32x2 ya, yc;
                ya.x = 0.f; ya.y = 0.f; yc = ya;
#pragma unroll
                for (int i = 0; i < 8; i++) {
                    f32x2 g = dtt2 * A2[i];
                    f32x2 e;
                    e.x = fexp2(g.x);
                    e.y = fexp2(g.y);
                    h2[i] = __builtin_elementwise_fma(e, h2[i], dtx2 * B2[i]);
                    if (i & 1)
                        yc = __builtin_elementwise_fma(h2[i], C2[i], yc);
                    else
                        ya = __builtin_elementwise_fma(h2[i], C2[i], ya);
                }
                f32x2 ys = ya + yc;
                wlp[(size_t)l * 512] = (ys.x + ys.y) + xv * dsk;
            }
            const float4* nr2 = (const float4*)(dr + (size_t)(l + 2) * 48);
#pragma unroll
            for (int i = 0; i < 12; i++) ((float4*)dbA)[i] = nr2[i];
            float xv2 = b2f(xp[(size_t)(l + 2) * 512]);
            if (l + 1 < SEGLEN) {
                float acc = dtproj8(dbB, w2, dtbv);
                float dtt = softplus_f(acc);
                dtp[(size_t)(l + 1) * 512] = dtt;
                sdt += dtt;
                float dtx = dtt * xv1;
                f32x2 dtt2, dtx2;
                dtt2.x = dtt; dtt2.y = dtt;
                dtx2.x = dtx; dtx2.y = dtx;
                const f32x2* B2 = (const f32x2*)(dbB + 16);
                const f32x2* C2 = (const f32x2*)(dbB + 32);
                f32x2 ya, yc;
                ya.x = 0.f; ya.y = 0.f; yc = ya;
#pragma unroll
                for (int i = 0; i < 8; i++) {
                    f32x2 g = dtt2 * A2[i];
                    f32x2 e;
                    e.x = fexp2(g.x);
                    e.y = fexp2(g.y);
                    h2[i] = __builtin_elementwise_fma(e, h2[i], dtx2 * B2[i]);
                    if (i & 1)
                        yc = __builtin_elementwise_fma(h2[i], C2[i], yc);
                    else
                        ya = __builtin_elementwise_fma(h2[i], C2[i], ya);
                }
                f32x2 ys = ya + yc;
                wlp[(size_t)(l + 1) * 512] = (ys.x + ys.y) + xv1 * dsk;
            }
            xv = xv2;
        }
#pragma unroll
        for (int i = 0; i < 8; i++) {
            lh[(seg * D_STATE + 2 * i + 0) * 64 + lane] = h2[i].x;
            lh[(seg * D_STATE + 2 * i + 1) * 64 + lane] = h2[i].y;
        }
        lsd[seg * 64 + lane] = sdt;
    }
    __syncthreads();
    // ---------------- phase 2: in-LDS prefix combine ----------------
    for (int it = tid; it < D_STATE * 64; it += 960) {
        int ch = it & 63, s = it >> 6;
        float As2 = -fexp2(A_log[(size_t)((dg << 6) + ch) * D_STATE + s] * L2E_F) * L2E_F;
        float hl[NSEG], sd[NSEG];
#pragma unroll
        for (int sg = 0; sg < NSEG; sg++) {
            hl[sg] = lh[(sg * D_STATE + s) * 64 + ch];
            sd[sg] = lsd[sg * 64 + ch];
        }
        float H = 0.f;
#pragma unroll
        for (int sg = 0; sg < NSEG; sg++) {
            lh[(sg * D_STATE + s) * 64 + ch] = H;
            H = fmaf(fexp2(As2 * sd[sg]), H, hl[sg]);
        }
    }
    __syncthreads();
    // ---------------- phase 3: decay-only correction  y = wl + C·(D⊙h_init) ----------------
    {
        f32x2 hc[8];
#pragma unroll
        for (int i = 0; i < 8; i++) {
            hc[i].x = lh[(seg * D_STATE + 2 * i + 0) * 64 + lane];
            hc[i].y = lh[(seg * D_STATE + 2 * i + 1) * 64 + lane];
        }
        float cbA[16], cbB[16];
#pragma unroll
        for (int i = 0; i < 4; i++) ((float4*)cbA)[i] = ((const float4*)(dr + 32))[i];
        float zv = b2f(zp[0]);
        float dt0 = dtp[0];
        float wl0 = wlp[0];
        for (int l = 0; l < SEGLEN; l += 2) {
            const float4* nr1 = (const float4*)(dr + (size_t)(l + 1) * 48 + 32);
#pragma unroll
            for (int i = 0; i < 4; i++) ((float4*)cbB)[i] = nr1[i];
            float zv1 = b2f(zp[(size_t)(l + 1) * 1024]);
            float dt1 = dtp[(size_t)(l + 1) * 512];
            float wl1 = wlp[(size_t)(l + 1) * 512];
            {
                float dtt = dt0;
                f32x2 dtt2;
                dtt2.x = dtt; dtt2.y = dtt;
                const f32x2* C2 = (const f32x2*)cbA;
                f32x2 ya, yc;
                ya.x = 0.f; ya.y = 0.f; yc = ya;
#pragma unroll
                for (int i = 0; i < 8; i++) {
                    f32x2 g = dtt2 * A2[i];
                    f32x2 e;
                    e.x = fexp2(g.x);
                    e.y = fexp2(g.y);
                    hc[i] = hc[i] * e;
                    if (i & 1)
                        yc = __builtin_elementwise_fma(hc[i], C2[i], yc);
                    else
                        ya = __builtin_elementwise_fma(hc[i], C2[i], ya);
                }
                f32x2 ys = ya + yc;
                float y = wl0 + (ys.x + ys.y);
                yp[(size_t)l * 512] = f2b(y * (zv * fast_sig(zv)));
            }
            const float4* nr2 = (const float4*)(dr + (size_t)(l + 2) * 48 + 32);
#pragma unroll
            for (int i = 0; i < 4; i++) ((float4*)cbA)[i] = nr2[i];
            float zv2 = b2f(zp[(size_t)(l + 2) * 1024]);
            float dt2 = dtp[(size_t)(l + 2) * 512];
            float wl2 = wlp[(size_t)(l + 2) * 512];
            if (l + 1 < SEGLEN) {
                float dtt = dt1;
                f32x2 dtt2;
                dtt2.x = dtt; dtt2.y = dtt;
                const f32x2* C2 = (const f32x2*)cbB;
                f32x2 ya, yc;
                ya.x = 0.f; ya.y = 0.f; yc = ya;
#pragma unroll
                for (int i = 0; i < 8; i++) {
                    f32x2 g = dtt2 * A2[i];
                    f32x2 e;
                    e.x = fexp2(g.x);
                    e.y = fexp2(g.y);
                    hc[i] = hc[i] * e;
                    if (i & 1)
                        yc = __builtin_elementwise_fma(hc[i], C2[i], yc);
                    else
                        ya = __builtin_elementwise_fma(hc[i], C2[i], ya);
                }
                f32x2 ys = ya + yc;
                float y = wl1 + (ys.x + ys.y);
                yp[(size_t)(l + 1) * 512] = f2b(y * (zv1 * fast_sig(zv1)));
            }
            zv = zv2; dt0 = dt2; wl0 = wl2;
        }
    }
}

extern "C" void kernel_launch(void* const* d_in, const int* in_sizes, int n_in,
                              void* d_out, int out_size, void* d_ws, size_t ws_size,
                              hipStream_t stream) {
    const float* coords   = (const float*)d_in[0];
    const float* emb_W    = (const float*)d_in[1];
    const float* emb_b    = (const float*)d_in[2];
    const float* ln_w     = (const float*)d_in[3];
    const float* ln_b     = (const float*)d_in[4];
    const float* in_W     = (const float*)d_in[5];
    const float* conv_W   = (const float*)d_in[6];
    const float* conv_b   = (const float*)d_in[7];
    const float* xproj_W  = (const float*)d_in[8];
    const float* dtproj_W = (const float*)d_in[9];
    const float* dtproj_b = (const float*)d_in[10];
    const float* A_log    = (const float*)d_in[11];
    const float* D_skip   = (const float*)d_in[12];
    const float* out_W    = (const float*)d_in[13];
    const float* normf_w  = (const float*)d_in[14];
    const float* normf_b  = (const float*)d_in[15];
    const float* head_W   = (const float*)d_in[16];
    float* out = (float*)d_out;

    const int T = NTOK;  // 9600
    float* resid = (float*)d_ws;
    float* dbl   = resid + (size_t)T * D_MODEL;
    float* dts   = dbl + (size_t)T * 48;
    float* wls   = dts + (size_t)T * D_INNER;
    unsigned short* hb     = (unsigned short*)(wls + (size_t)T * D_INNER);
    unsigned short* xzb    = hb + (size_t)T * D_MODEL;
    unsigned short* xcb    = xzb + (size_t)T * 2 * D_INNER;
    unsigned short* yb     = xcb + (size_t)T * D_INNER;
    unsigned short* wb_in  = yb + (size_t)T * D_INNER;
    unsigned short* wb_xp  = wb_in + (size_t)N_LAYERS * 2 * D_INNER * D_MODEL;
    unsigned short* wb_out = wb_xp + (size_t)N_LAYERS * 48 * D_INNER;
    unsigned short* wb_hd  = wb_out + (size_t)N_LAYERS * D_MODEL * D_INNER;

    cvt4_kernel<<<256, 256, 0, stream>>>(
        in_W, wb_in, N_LAYERS * 2 * D_INNER * D_MODEL,
        xproj_W, wb_xp, N_LAYERS * 48 * D_INNER,
        out_W, wb_out, N_LAYERS * D_MODEL * D_INNER,
        head_W, wb_hd, CITY * D_MODEL);

    embed_ln_kernel<<<T, D_MODEL, 0, stream>>>(coords, emb_W, emb_b, ln_w, ln_b, resid, hb);

    for (int i = 0; i < N_LAYERS; i++) {
        // in_proj: (9600,256) x (1024,256)^T -> (9600,1024) bf16
        gemm_mfma<128, 128, false, true><<<dim3(T / 128, 8), 256, 0, stream>>>(
            hb, wb_in + (size_t)i * 2 * D_INNER * D_MODEL, xzb, 2 * D_INNER, D_MODEL);
        // fused conv+SiLU+xproj: emits xcb (bf16) and dbl (f32, 48 cols)
        xproj_conv<<<T / 64, 256, 0, stream>>>(
            xzb, conv_W + i * D_INNER * D_CONV, conv_b + i * D_INNER,
            wb_xp + (size_t)i * 48 * D_INNER, xcb, dbl);
        // scan -> yb bf16 (dtt + local-y round-trip via dts/wls)
        scan_block<<<dim3(BATCH, 8), 960, 0, stream>>>(
            xcb, dbl, xzb, A_log + (size_t)i * D_INNER * D_STATE, D_skip + i * D_INNER,
            dtproj_W + (size_t)i * D_INNER * DT_RANK, dtproj_b + i * D_INNER, dts, wls, yb);
        // out_proj + residual + LN (layers 0-2) / RMS+head (layer 3) fused
        if (i < N_LAYERS - 1)
            gemm_out_ln<false, false><<<T / 64, 256, 0, stream>>>(
                yb, wb_out + (size_t)i * D_MODEL * D_INNER, resid,
                ln_w + (i + 1) * D_MODEL, ln_b + (i + 1) * D_MODEL, hb, nullptr, nullptr);
        else
            gemm_out_ln<true, true><<<T / 64, 256, 0, stream>>>(
                yb, wb_out + (size_t)i * D_MODEL * D_INNER, resid,
                normf_w, normf_b, hb, wb_hd, out);
    }
}

// Round 10
// 456.603 us; speedup vs baseline: 1.0228x; 1.0228x over previous
//
#include <hip/hip_runtime.h>
#include <hip/hip_bf16.h>
#include <math.h>

#define D_MODEL 256
#define D_INNER 512
#define D_STATE 16
#define D_CONV 4
#define DT_RANK 16
#define N_LAYERS 4
#define CITY 300
#define BATCH 32
#define SEQ 300
#define NTOK (BATCH * SEQ)   // 9600
#define NSEG 15
#define SEGLEN (SEQ / NSEG)  // 20

typedef __attribute__((ext_vector_type(8))) short short8v;
typedef __attribute__((ext_vector_type(4))) float f32x4;
typedef __attribute__((ext_vector_type(2))) float f32x2;

#define L2E_F 1.44269504088896340736f
#define LN2_F 0.69314718055994530942f

__device__ __forceinline__ float fexp2(float x) { return __builtin_amdgcn_exp2f(x); }
__device__ __forceinline__ float flog2(float x) { return __builtin_amdgcn_logf(x); }

__device__ __forceinline__ float fast_sig(float x) {
    return __builtin_amdgcn_rcpf(1.f + fexp2(-x * L2E_F));
}

__device__ __forceinline__ float softplus_f(float x) {
    float t = fexp2(-fabsf(x) * L2E_F);
    return fmaxf(x, 0.f) + flog2(1.f + t) * LN2_F;
}

__device__ __forceinline__ unsigned short f2b(float a) {
    __hip_bfloat16 h = __float2bfloat16(a);
    return *reinterpret_cast<unsigned short*>(&h);
}

__device__ __forceinline__ float b2f(unsigned short u) {
    unsigned int x = ((unsigned int)u) << 16;
    return __uint_as_float(x);
}

// packed dt-projection: sum_{r<16} rb[r]*dW[r] + dtb   (8 x v_pk_fma_f32)
__device__ __forceinline__ float dtproj8(const float* rb, const f32x2* w2, float dtbv) {
    const f32x2* r2 = (const f32x2*)rb;
    f32x2 a0, a1, a2, a3;
    a0.x = dtbv; a0.y = 0.f;
    a1.x = 0.f; a1.y = 0.f;
    a2 = a1; a3 = a1;
    a0 = __builtin_elementwise_fma(r2[0], w2[0], a0);
    a1 = __builtin_elementwise_fma(r2[1], w2[1], a1);
    a2 = __builtin_elementwise_fma(r2[2], w2[2], a2);
    a3 = __builtin_elementwise_fma(r2[3], w2[3], a3);
    a0 = __builtin_elementwise_fma(r2[4], w2[4], a0);
    a1 = __builtin_elementwise_fma(r2[5], w2[5], a1);
    a2 = __builtin_elementwise_fma(r2[6], w2[6], a2);
    a3 = __builtin_elementwise_fma(r2[7], w2[7], a3);
    f32x2 s = (a0 + a1) + (a2 + a3);
    return s.x + s.y;
}

// ---------------- all weight conversions, vectorized ----------------
__global__ void cvt4_kernel(const float* __restrict__ s0, unsigned short* __restrict__ d0, int n0,
                            const float* __restrict__ s1, unsigned short* __restrict__ d1, int n1,
                            const float* __restrict__ s2, unsigned short* __restrict__ d2, int n2,
                            const float* __restrict__ s3, unsigned short* __restrict__ d3, int n3) {
    int stride = gridDim.x * blockDim.x;
    int tid = blockIdx.x * blockDim.x + threadIdx.x;
    for (int i = tid; i < n0 / 4; i += stride) {
        float4 v = ((const float4*)s0)[i];
        ushort4 o; o.x = f2b(v.x); o.y = f2b(v.y); o.z = f2b(v.z); o.w = f2b(v.w);
        ((ushort4*)d0)[i] = o;
    }
    for (int i = tid; i < n1 / 4; i += stride) {
        float4 v = ((const float4*)s1)[i];
        ushort4 o; o.x = f2b(v.x); o.y = f2b(v.y); o.z = f2b(v.z); o.w = f2b(v.w);
        ((ushort4*)d1)[i] = o;
    }
    for (int i = tid; i < n2 / 4; i += stride) {
        float4 v = ((const float4*)s2)[i];
        ushort4 o; o.x = f2b(v.x); o.y = f2b(v.y); o.z = f2b(v.z); o.w = f2b(v.w);
        ((ushort4*)d2)[i] = o;
    }
    for (int i = tid; i < n3 / 4; i += stride) {
        float4 v = ((const float4*)s3)[i];
        ushort4 o; o.x = f2b(v.x); o.y = f2b(v.y); o.z = f2b(v.z); o.w = f2b(v.w);
        ((ushort4*)d3)[i] = o;
    }
}

// ---------------- embedding + layer-0 residual init + LN (fused) ----------------
__global__ void embed_ln_kernel(const float* __restrict__ coords,
                                const float* __restrict__ eW,
                                const float* __restrict__ eb,
                                const float* __restrict__ w,
                                const float* __restrict__ b,
                                float* __restrict__ resid,
                                unsigned short* __restrict__ hb) {
    int t = blockIdx.x, d = threadIdx.x;
    float c0 = coords[t * 2 + 0];
    float c1 = coords[t * 2 + 1];
    float r = c0 * eW[d * 2 + 0] + c1 * eW[d * 2 + 1] + eb[d];
    resid[t * D_MODEL + d] = r;
    float s1 = r, s2 = r * r;
#pragma unroll
    for (int m = 1; m < 64; m <<= 1) {
        s1 += __shfl_xor(s1, m);
        s2 += __shfl_xor(s2, m);
    }
    __shared__ float p1[4], p2[4];
    if ((d & 63) == 0) { p1[d >> 6] = s1; p2[d >> 6] = s2; }
    __syncthreads();
    s1 = (p1[0] + p1[1]) + (p1[2] + p1[3]);
    s2 = (p2[0] + p2[1]) + (p2[2] + p2[3]);
    float mean = s1 * (1.f / D_MODEL);
    float var = s2 * (1.f / D_MODEL) - mean * mean;
    hb[t * D_MODEL + d] = f2b((r - mean) * rsqrtf(var + 1e-5f) * w[d] + b[d]);
}

// ------------- bf16-in MFMA GEMM: C[t,n] = sum_k A[t,k] * W[n,k] -------------
template <int BM, int BN, bool GN, bool OB>
__global__ __launch_bounds__(256, 2) void gemm_mfma(const unsigned short* __restrict__ A,
                                                    const unsigned short* __restrict__ W,
                                                    void* __restrict__ C, int N, int K) {
    constexpr int TI = BM / 32;
    constexpr int TJ = BN / 32;
    __shared__ short Als[BM * 32];
    __shared__ short Bls[BN * 32];
    const int tid = threadIdx.x;
    const int lane = tid & 63, wid = tid >> 6;
    const int wr = wid >> 1, wc = wid & 1;
    const int t0 = blockIdx.x * BM, n0 = blockIdx.y * BN;
    f32x4 acc[TI][TJ] = {};

    for (int k0 = 0; k0 < K; k0 += 32) {
#pragma unroll
        for (int it = 0; it < BM / 64; ++it) {
            int s = tid + it * 256;
            int m = s >> 2, q = s & 3;
            uint4 p = *(const uint4*)(A + (size_t)(t0 + m) * K + k0 + q * 8);
            *(uint4*)&Als[(((m >> 4) * 4 + q) * 16 + (m & 15)) * 8] = p;
        }
#pragma unroll
        for (int it = 0; it < BN / 64; ++it) {
            int s = tid + it * 256;
            int n = s >> 2, q = s & 3;
            int nrow = n0 + n;
            uint4 p = make_uint4(0u, 0u, 0u, 0u);
            if (!GN || nrow < N)
                p = *(const uint4*)(W + (size_t)nrow * K + k0 + q * 8);
            *(uint4*)&Bls[(((n >> 4) * 4 + q) * 16 + (n & 15)) * 8] = p;
        }
        __syncthreads();
        short8v af[TI], bf[TJ];
#pragma unroll
        for (int i = 0; i < TI; i++)
            af[i] = *(const short8v*)&Als[(wr * TI + i) * 512 + lane * 8];
#pragma unroll
        for (int j = 0; j < TJ; j++)
            bf[j] = *(const short8v*)&Bls[(wc * TJ + j) * 512 + lane * 8];
#pragma unroll
        for (int i = 0; i < TI; i++)
#pragma unroll
            for (int j = 0; j < TJ; j++)
                acc[i][j] = __builtin_amdgcn_mfma_f32_16x16x32_bf16(
                    af[i], bf[j], acc[i][j], 0, 0, 0);
        __syncthreads();
    }
    const int rq = lane >> 4, cn = lane & 15;
#pragma unroll
    for (int i = 0; i < TI; i++) {
        int trow = t0 + wr * (BM / 2) + i * 16 + rq * 4;
#pragma unroll
        for (int j = 0; j < TJ; j++) {
            int ncol = n0 + wc * (BN / 2) + j * 16 + cn;
            if (!GN || ncol < N) {
#pragma unroll
                for (int reg = 0; reg < 4; reg++) {
                    if constexpr (OB)
                        ((unsigned short*)C)[(size_t)(trow + reg) * N + ncol] =
                            f2b(acc[i][j][reg]);
                    else
                        ((float*)C)[(size_t)(trow + reg) * N + ncol] = acc[i][j][reg];
                }
            }
        }
    }
}

// ===== fused causal conv(k=4)+SiLU + xproj GEMM; also emits xcb (bf16 conv out) =====
__global__ __launch_bounds__(256, 2) void xproj_conv(
    const unsigned short* __restrict__ xzb,
    const float* __restrict__ cW, const float* __restrict__ cb,
    const unsigned short* __restrict__ W,
    unsigned short* __restrict__ xcb, float* __restrict__ dblo) {
    constexpr int TI = 2, TJ = 2;   // BM=64, BN=64
    const int K = D_INNER, N = 48;
    __shared__ short Als[64 * 32];
    __shared__ short Bls[64 * 32];
    __shared__ float cwL[D_INNER * 4];   // 8 KB: [ch*4 + tap]
    __shared__ float cbL[D_INNER];       // 2 KB
    const int tid = threadIdx.x;
    const int lane = tid & 63, wid = tid >> 6;
    const int wr = wid >> 1, wc = wid & 1;
    const int t0 = blockIdx.x * 64;

    for (int i = tid; i < D_INNER; i += 256) {
        ((float4*)cwL)[i] = ((const float4*)cW)[i];
        cbL[i] = cb[i];
    }
    __syncthreads();

    f32x4 acc[TI][TJ] = {};
    const int m = tid >> 2, q = tid & 3;
    const int t = t0 + m;
    const int l = t % SEQ;

    for (int k0 = 0; k0 < K; k0 += 32) {
        {
            const int ch0 = k0 + q * 8;
            const unsigned short* xr = xzb + (size_t)t * 1024 + ch0;
            uint4 u0 = make_uint4(0u, 0u, 0u, 0u), u1 = u0, u2 = u0, u3;
            if (l >= 3) u0 = *(const uint4*)(xr - 3 * 1024);
            if (l >= 2) u1 = *(const uint4*)(xr - 2 * 1024);
            if (l >= 1) u2 = *(const uint4*)(xr - 1 * 1024);
            u3 = *(const uint4*)xr;
            unsigned int ow0, ow1, ow2, ow3;
#pragma unroll
            for (int c2 = 0; c2 < 4; c2++) {
                unsigned int w0 = (c2 == 0) ? u0.x : (c2 == 1) ? u0.y : (c2 == 2) ? u0.z : u0.w;
                unsigned int w1 = (c2 == 0) ? u1.x : (c2 == 1) ? u1.y : (c2 == 2) ? u1.z : u1.w;
                unsigned int w2 = (c2 == 0) ? u2.x : (c2 == 1) ? u2.y : (c2 == 2) ? u2.z : u2.w;
                unsigned int w3 = (c2 == 0) ? u3.x : (c2 == 1) ? u3.y : (c2 == 2) ? u3.z : u3.w;
                int chA = ch0 + c2 * 2, chB = chA + 1;
                float4 wvA = *(const float4*)&cwL[chA * 4];
                float4 wvB = *(const float4*)&cwL[chB * 4];
                float aA = cbL[chA], aB = cbL[chB];
                aA = fmaf(b2f((unsigned short)(w0 & 0xffffu)), wvA.x, aA);
                aB = fmaf(b2f((unsigned short)(w0 >> 16)), wvB.x, aB);
                aA = fmaf(b2f((unsigned short)(w1 & 0xffffu)), wvA.y, aA);
                aB = fmaf(b2f((unsigned short)(w1 >> 16)), wvB.y, aB);
                aA = fmaf(b2f((unsigned short)(w2 & 0xffffu)), wvA.z, aA);
                aB = fmaf(b2f((unsigned short)(w2 >> 16)), wvB.z, aB);
                aA = fmaf(b2f((unsigned short)(w3 & 0xffffu)), wvA.w, aA);
                aB = fmaf(b2f((unsigned short)(w3 >> 16)), wvB.w, aB);
                aA = aA * fast_sig(aA);
                aB = aB * fast_sig(aB);
                unsigned int pk = (unsigned int)f2b(aA) | ((unsigned int)f2b(aB) << 16);
                if (c2 == 0) ow0 = pk; else if (c2 == 1) ow1 = pk; else if (c2 == 2) ow2 = pk; else ow3 = pk;
            }
            uint4 pk4 = make_uint4(ow0, ow1, ow2, ow3);
            *(uint4*)&Als[(((m >> 4) * 4 + q) * 16 + (m & 15)) * 8] = pk4;
            *(uint4*)(xcb + (size_t)t * 512 + ch0) = pk4;
        }
        {
            int n = tid >> 2;
            uint4 p = make_uint4(0u, 0u, 0u, 0u);
            if (n < N) p = *(const uint4*)(W + (size_t)n * K + k0 + q * 8);
            *(uint4*)&Bls[(((n >> 4) * 4 + q) * 16 + (n & 15)) * 8] = p;
        }
        __syncthreads();
        short8v af[TI], bf[TJ];
#pragma unroll
        for (int i = 0; i < TI; i++)
            af[i] = *(const short8v*)&Als[(wr * TI + i) * 512 + lane * 8];
#pragma unroll
        for (int j = 0; j < TJ; j++)
            bf[j] = *(const short8v*)&Bls[(wc * TJ + j) * 512 + lane * 8];
#pragma unroll
        for (int i = 0; i < TI; i++)
#pragma unroll
            for (int j = 0; j < TJ; j++)
                acc[i][j] = __builtin_amdgcn_mfma_f32_16x16x32_bf16(
                    af[i], bf[j], acc[i][j], 0, 0, 0);
        __syncthreads();
    }
    const int rq = lane >> 4, cn = lane & 15;
#pragma unroll
    for (int i = 0; i < TI; i++) {
        int trow = t0 + (wr * TI + i) * 16 + rq * 4;
#pragma unroll
        for (int j = 0; j < TJ; j++) {
            int ncol = wc * 32 + j * 16 + cn;
            if (ncol < N) {
#pragma unroll
                for (int reg = 0; reg < 4; reg++)
                    dblo[(size_t)(trow + reg) * N + ncol] = acc[i][j][reg];
            }
        }
    }
}

// ------------- out_proj GEMM + residual add + LN/RMS fused epilogue -------------
template <bool RMS>
__global__ __launch_bounds__(256, 2) void gemm_out_ln(const unsigned short* __restrict__ A,
                                                      const unsigned short* __restrict__ W,
                                                      float* __restrict__ resid,
                                                      const float* __restrict__ w,
                                                      const float* __restrict__ b,
                                                      unsigned short* __restrict__ hb) {
    constexpr int TI = 2, TJ = 8;
    const int K = D_INNER;
    __shared__ short Als[64 * 32];
    __shared__ short Bls[256 * 32];
    __shared__ float rs1[2][64], rs2[2][64];
    const int tid = threadIdx.x;
    const int lane = tid & 63, wid = tid >> 6;
    const int wr = wid >> 1, wc = wid & 1;
    const int t0 = blockIdx.x * 64;
    f32x4 acc[TI][TJ] = {};

    for (int k0 = 0; k0 < K; k0 += 32) {
        {
            int s = tid;
            int m = s >> 2, q = s & 3;
            uint4 p = *(const uint4*)(A + (size_t)(t0 + m) * K + k0 + q * 8);
            *(uint4*)&Als[(((m >> 4) * 4 + q) * 16 + (m & 15)) * 8] = p;
        }
#pragma unroll
        for (int it = 0; it < 4; ++it) {
            int s = tid + it * 256;
            int n = s >> 2, q = s & 3;
            uint4 p = *(const uint4*)(W + (size_t)n * K + k0 + q * 8);
            *(uint4*)&Bls[(((n >> 4) * 4 + q) * 16 + (n & 15)) * 8] = p;
        }
        __syncthreads();
        short8v af[TI], bf[TJ];
#pragma unroll
        for (int i = 0; i < TI; i++)
            af[i] = *(const short8v*)&Als[(wr * TI + i) * 512 + lane * 8];
#pragma unroll
        for (int j = 0; j < TJ; j++)
            bf[j] = *(const short8v*)&Bls[(wc * TJ + j) * 512 + lane * 8];
#pragma unroll
        for (int i = 0; i < TI; i++)
#pragma unroll
            for (int j = 0; j < TJ; j++)
                acc[i][j] = __builtin_amdgcn_mfma_f32_16x16x32_bf16(
                    af[i], bf[j], acc[i][j], 0, 0, 0);
        __syncthreads();
    }
    const int rq = lane >> 4, cn = lane & 15;
    float s1p[TI][4], s2p[TI][4];
#pragma unroll
    for (int i = 0; i < TI; i++) {
        int trow = t0 + wr * 32 + i * 16 + rq * 4;
#pragma unroll
        for (int reg = 0; reg < 4; reg++) { s1p[i][reg] = 0.f; s2p[i][reg] = 0.f; }
#pragma unroll
        for (int j = 0; j < TJ; j++) {
            int c = wc * 128 + j * 16 + cn;
#pragma unroll
            for (int reg = 0; reg < 4; reg++) {
                float rv = acc[i][j][reg] + resid[(size_t)(trow + reg) * D_MODEL + c];
                acc[i][j][reg] = rv;
                s1p[i][reg] += rv;
                s2p[i][reg] = fmaf(rv, rv, s2p[i][reg]);
            }
        }
    }
#pragma unroll
    for (int m = 1; m < 16; m <<= 1) {
#pragma unroll
        for (int i = 0; i < TI; i++)
#pragma unroll
            for (int reg = 0; reg < 4; reg++) {
                s1p[i][reg] += __shfl_xor(s1p[i][reg], m);
                s2p[i][reg] += __shfl_xor(s2p[i][reg], m);
            }
    }
    if (cn == 0) {
#pragma unroll
        for (int i = 0; i < TI; i++)
#pragma unroll
            for (int reg = 0; reg < 4; reg++) {
                int rloc = wr * 32 + i * 16 + rq * 4 + reg;
                rs1[wc][rloc] = s1p[i][reg];
                rs2[wc][rloc] = s2p[i][reg];
            }
    }
    __syncthreads();
    float wv[TJ], bv[TJ];
#pragma unroll
    for (int j = 0; j < TJ; j++) {
        int c = wc * 128 + j * 16 + cn;
        wv[j] = w[c];
        bv[j] = b[c];
    }
#pragma unroll
    for (int i = 0; i < TI; i++) {
        int trow = t0 + wr * 32 + i * 16 + rq * 4;
#pragma unroll
        for (int reg = 0; reg < 4; reg++) {
            int rloc = wr * 32 + i * 16 + rq * 4 + reg;
            float S1 = rs1[0][rloc] + rs1[1][rloc];
            float S2 = rs2[0][rloc] + rs2[1][rloc];
            float mean, rstd;
            if constexpr (RMS) {
                mean = 0.f;
                rstd = rsqrtf(S2 * (1.f / D_MODEL) + 1e-5f);
            } else {
                mean = S1 * (1.f / D_MODEL);
                float var = S2 * (1.f / D_MODEL) - mean * mean;
                rstd = rsqrtf(var + 1e-5f);
            }
#pragma unroll
            for (int j = 0; j < TJ; j++) {
                int c = wc * 128 + j * 16 + cn;
                float rv = acc[i][j][reg];
                hb[(size_t)(trow + reg) * D_MODEL + c] =
                    f2b((rv - mean) * rstd * wv[j] + bv[j]);
                if constexpr (!RMS)
                    resid[(size_t)(trow + reg) * D_MODEL + c] = rv;
            }
        }
    }
}

// ========== block-local 3-phase scan; packed-FP32 (v_pk_fma_f32) state loops ==========
// NOTE: seg MUST be wave-uniform (readfirstlane) so the dbl row addresses are
// lane-invariant -> compiler scalarizes row buffers into SGPRs (s_load_dwordx4).
// Latency-bound at 1 block/CU: VALU cuts (R9), occupancy remaps (R3), and register
// carry (R2) all failed to improve it. Do not touch without new counter evidence.
__global__ __launch_bounds__(960) void scan_block(
    const unsigned short* __restrict__ xcb, const float* __restrict__ dbl,
    const unsigned short* __restrict__ xzb,
    const float* __restrict__ A_log, const float* __restrict__ Dskip,
    const float* __restrict__ dtW, const float* __restrict__ dtb,
    float* __restrict__ dts, unsigned short* __restrict__ yb) {
    __shared__ float lh[NSEG * D_STATE * 64];
    __shared__ float lsd[NSEG * 64];
    const int b = blockIdx.x, dg = blockIdx.y;
    const int tid = threadIdx.x;
    const int lane = tid & 63;
    const int seg = __builtin_amdgcn_readfirstlane(tid >> 6);
    const int d = (dg << 6) + lane;
    f32x2 A2[8], w2[8];
#pragma unroll
    for (int s4 = 0; s4 < 4; s4++) {
        float4 v = *(const float4*)(A_log + (size_t)d * D_STATE + s4 * 4);
        f32x2 pa, pb;
        pa.x = -fexp2(v.x * L2E_F) * L2E_F;
        pa.y = -fexp2(v.y * L2E_F) * L2E_F;
        pb.x = -fexp2(v.z * L2E_F) * L2E_F;
        pb.y = -fexp2(v.w * L2E_F) * L2E_F;
        A2[s4 * 2 + 0] = pa;
        A2[s4 * 2 + 1] = pb;
        float4 w = *(const float4*)(dtW + (size_t)d * DT_RANK + s4 * 4);
        f32x2 qa, qb;
        qa.x = w.x; qa.y = w.y;
        qb.x = w.z; qb.y = w.w;
        w2[s4 * 2 + 0] = qa;
        w2[s4 * 2 + 1] = qb;
    }
    const float dtbv = dtb[d], dsk = Dskip[d];
    const size_t tb = (size_t)b * SEQ + (size_t)seg * SEGLEN;
    const float* __restrict__ dr = dbl + tb * 48;
    const unsigned short* __restrict__ xp = xcb + tb * 512 + d;
    const unsigned short* __restrict__ zp = xzb + tb * 1024 + 512 + d;
    float* __restrict__ dtp = dts + tb * 512 + d;
    unsigned short* __restrict__ yp = yb + tb * 512 + d;

    // ---------------- phase 1: local scan from h=0; record dtt ----------------
    {
        f32x2 h2[8];
#pragma unroll
        for (int i = 0; i < 8; i++) { h2[i].x = 0.f; h2[i].y = 0.f; }
        float sdt = 0.f;
        float dbA[32], dbB[32];
#pragma unroll
        for (int i = 0; i < 8; i++) ((float4*)dbA)[i] = ((const float4*)dr)[i];
        float xv = b2f(xp[0]);
        for (int l = 0; l < SEGLEN; l += 2) {
            const float4* nr1 = (const float4*)(dr + (size_t)(l + 1) * 48);
#pragma unroll
            for (int i = 0; i < 8; i++) ((float4*)dbB)[i] = nr1[i];
            float xv1 = b2f(xp[(size_t)(l + 1) * 512]);
            {
                float acc = dtproj8(dbA, w2, dtbv);
                float dtt = softplus_f(acc);
                dtp[(size_t)l * 512] = dtt;
                sdt += dtt;
                float dtx = dtt * xv;
                f32x2 dtt2, dtx2;
                dtt2.x = dtt; dtt2.y = dtt;
                dtx2.x = dtx; dtx2.y = dtx;
                const f32x2* B2 = (const f32x2*)(dbA + 16);
#pragma unroll
                for (int i = 0; i < 8; i++) {
                    f32x2 g = dtt2 * A2[i];
                    f32x2 e;
                    e.x = fexp2(g.x);
                    e.y = fexp2(g.y);
                    h2[i] = __builtin_elementwise_fma(e, h2[i], dtx2 * B2[i]);
                }
            }
            const float4* nr2 = (const float4*)(dr + (size_t)(l + 2) * 48);
#pragma unroll
            for (int i = 0; i < 8; i++) ((float4*)dbA)[i] = nr2[i];
            float xv2 = b2f(xp[(size_t)(l + 2) * 512]);
            if (l + 1 < SEGLEN) {
                float acc = dtproj8(dbB, w2, dtbv);
                float dtt = softplus_f(acc);
                dtp[(size_t)(l + 1) * 512] = dtt;
                sdt += dtt;
                float dtx = dtt * xv1;
                f32x2 dtt2, dtx2;
                dtt2.x = dtt; dtt2.y = dtt;
                dtx2.x = dtx; dtx2.y = dtx;
                const f32x2* B2 = (const f32x2*)(dbB + 16);
#pragma unroll
                for (int i = 0; i < 8; i++) {
                    f32x2 g = dtt2 * A2[i];
                    f32x2 e;
                    e.x = fexp2(g.x);
                    e.y = fexp2(g.y);
                    h2[i] = __builtin_elementwise_fma(e, h2[i], dtx2 * B2[i]);
                }
            }
            xv = xv2;
        }
#pragma unroll
        for (int i = 0; i < 8; i++) {
            lh[(seg * D_STATE + 2 * i + 0) * 64 + lane] = h2[i].x;
            lh[(seg * D_STATE + 2 * i + 1) * 64 + lane] = h2[i].y;
        }
        lsd[seg * 64 + lane] = sdt;
    }
    __syncthreads();
    // ---------------- phase 2: in-LDS prefix combine (batched reads) ----------------
    for (int it = tid; it < D_STATE * 64; it += 960) {
        int ch = it & 63, s = it >> 6;
        float As2 = -fexp2(A_log[(size_t)((dg << 6) + ch) * D_STATE + s] * L2E_F) * L2E_F;
        float hl[NSEG], sd[NSEG];
#pragma unroll
        for (int sg = 0; sg < NSEG; sg++) {
            hl[sg] = lh[(sg * D_STATE + s) * 64 + ch];
            sd[sg] = lsd[sg * 64 + ch];
        }
        float H = 0.f;
#pragma unroll
        for (int sg = 0; sg < NSEG; sg++) {
            lh[(sg * D_STATE + s) * 64 + ch] = H;
            H = fmaf(fexp2(As2 * sd[sg]), H, hl[sg]);
        }
    }
    __syncthreads();
    // ---------------- phase 3: re-scan from initial state (dtt cached; B,C rows only) ----------------
    {
        f32x2 h2[8];
#pragma unroll
        for (int i = 0; i < 8; i++) {
            h2[i].x = lh[(seg * D_STATE + 2 * i + 0) * 64 + lane];
            h2[i].y = lh[(seg * D_STATE + 2 * i + 1) * 64 + lane];
        }
        float dbA[32], dbB[32];
#pragma unroll
        for (int i = 0; i < 8; i++) ((float4*)dbA)[i] = ((const float4*)(dr + 16))[i];
        float xv = b2f(xp[0]), zv = b2f(zp[0]);
        float dt0 = dtp[0];
        for (int l = 0; l < SEGLEN; l += 2) {
            const float4* nr1 = (const float4*)(dr + (size_t)(l + 1) * 48 + 16);
#pragma unroll
            for (int i = 0; i < 8; i++) ((float4*)dbB)[i] = nr1[i];
            float xv1 = b2f(xp[(size_t)(l + 1) * 512]);
            float zv1 = b2f(zp[(size_t)(l + 1) * 1024]);
            float dt1 = dtp[(size_t)(l + 1) * 512];
            {
                float dtt = dt0;
                float dtx = dtt * xv;
                f32x2 dtt2, dtx2;
                dtt2.x = dtt; dtt2.y = dtt;
                dtx2.x = dtx; dtx2.y = dtx;
                f32x2 ya, yc;
                ya.x = 0.f; ya.y = 0.f; yc = ya;
                const f32x2* B2 = (const f32x2*)dbA;
                const f32x2* C2 = (const f32x2*)(dbA + 16);
#pragma unroll
                for (int i = 0; i < 8; i++) {
                    f32x2 g = dtt2 * A2[i];
                    f32x2 e;
                    e.x = fexp2(g.x);
                    e.y = fexp2(g.y);
                    h2[i] = __builtin_elementwise_fma(e, h2[i], dtx2 * B2[i]);
                    if (i & 1)
                        yc = __builtin_elementwise_fma(h2[i], C2[i], yc);
                    else
                        ya = __builtin_elementwise_fma(h2[i], C2[i], ya);
                }
                f32x2 ys = ya + yc;
                float y = ys.x + ys.y;
                yp[(size_t)l * 512] = f2b((y + xv * dsk) * (zv * fast_sig(zv)));
            }
            const float4* nr2 = (const float4*)(dr + (size_t)(l + 2) * 48 + 16);
#pragma unroll
            for (int i = 0; i < 8; i++) ((float4*)dbA)[i] = nr2[i];
            float xv2 = b2f(xp[(size_t)(l + 2) * 512]);
            float zv2 = b2f(zp[(size_t)(l + 2) * 1024]);
            float dt2 = dtp[(size_t)(l + 2) * 512];
            if (l + 1 < SEGLEN) {
                float dtt = dt1;
                float dtx = dtt * xv1;
                f32x2 dtt2, dtx2;
                dtt2.x = dtt; dtt2.y = dtt;
                dtx2.x = dtx; dtx2.y = dtx;
                f32x2 ya, yc;
                ya.x = 0.f; ya.y = 0.f; yc = ya;
                const f32x2* B2 = (const f32x2*)dbB;
                const f32x2* C2 = (const f32x2*)(dbB + 16);
#pragma unroll
                for (int i = 0; i < 8; i++) {
                    f32x2 g = dtt2 * A2[i];
                    f32x2 e;
                    e.x = fexp2(g.x);
                    e.y = fexp2(g.y);
                    h2[i] = __builtin_elementwise_fma(e, h2[i], dtx2 * B2[i]);
                    if (i & 1)
                        yc = __builtin_elementwise_fma(h2[i], C2[i], yc);
                    else
                        ya = __builtin_elementwise_fma(h2[i], C2[i], ya);
                }
                f32x2 ys = ya + yc;
                float y = ys.x + ys.y;
                yp[(size_t)(l + 1) * 512] = f2b((y + xv1 * dsk) * (zv1 * fast_sig(zv1)));
            }
            xv = xv2; zv = zv2; dt0 = dt2;
        }
    }
}

extern "C" void kernel_launch(void* const* d_in, const int* in_sizes, int n_in,
                              void* d_out, int out_size, void* d_ws, size_t ws_size,
                              hipStream_t stream) {
    const float* coords   = (const float*)d_in[0];
    const float* emb_W    = (const float*)d_in[1];
    const float* emb_b    = (const float*)d_in[2];
    const float* ln_w     = (const float*)d_in[3];
    const float* ln_b     = (const float*)d_in[4];
    const float* in_W     = (const float*)d_in[5];
    const float* conv_W   = (const float*)d_in[6];
    const float* conv_b   = (const float*)d_in[7];
    const float* xproj_W  = (const float*)d_in[8];
    const float* dtproj_W = (const float*)d_in[9];
    const float* dtproj_b = (const float*)d_in[10];
    const float* A_log    = (const float*)d_in[11];
    const float* D_skip   = (const float*)d_in[12];
    const float* out_W    = (const float*)d_in[13];
    const float* normf_w  = (const float*)d_in[14];
    const float* normf_b  = (const float*)d_in[15];
    const float* head_W   = (const float*)d_in[16];
    float* out = (float*)d_out;

    const int T = NTOK;  // 9600
    float* resid = (float*)d_ws;
    float* dbl   = resid + (size_t)T * D_MODEL;
    float* dts   = dbl + (size_t)T * 48;
    unsigned short* hb     = (unsigned short*)(dts + (size_t)T * D_INNER);
    unsigned short* xzb    = hb + (size_t)T * D_MODEL;
    unsigned short* xcb    = xzb + (size_t)T * 2 * D_INNER;
    unsigned short* yb     = xcb + (size_t)T * D_INNER;
    unsigned short* wb_in  = yb + (size_t)T * D_INNER;
    unsigned short* wb_xp  = wb_in + (size_t)N_LAYERS * 2 * D_INNER * D_MODEL;
    unsigned short* wb_out = wb_xp + (size_t)N_LAYERS * 48 * D_INNER;
    unsigned short* wb_hd  = wb_out + (size_t)N_LAYERS * D_MODEL * D_INNER;

    cvt4_kernel<<<256, 256, 0, stream>>>(
        in_W, wb_in, N_LAYERS * 2 * D_INNER * D_MODEL,
        xproj_W, wb_xp, N_LAYERS * 48 * D_INNER,
        out_W, wb_out, N_LAYERS * D_MODEL * D_INNER,
        head_W, wb_hd, CITY * D_MODEL);

    embed_ln_kernel<<<T, D_MODEL, 0, stream>>>(coords, emb_W, emb_b, ln_w, ln_b, resid, hb);

    for (int i = 0; i < N_LAYERS; i++) {
        // in_proj: (9600,256) x (1024,256)^T -> (9600,1024) bf16
        gemm_mfma<128, 128, false, true><<<dim3(T / 128, 8), 256, 0, stream>>>(
            hb, wb_in + (size_t)i * 2 * D_INNER * D_MODEL, xzb, 2 * D_INNER, D_MODEL);
        // fused conv+SiLU+xproj: emits xcb (bf16) and dbl (f32, 48 cols)
        xproj_conv<<<T / 64, 256, 0, stream>>>(
            xzb, conv_W + i * D_INNER * D_CONV, conv_b + i * D_INNER,
            wb_xp + (size_t)i * 48 * D_INNER, xcb, dbl);
        // scan -> yb bf16 (dtt stashed in dts)
        scan_block<<<dim3(BATCH, 8), 960, 0, stream>>>(
            xcb, dbl, xzb, A_log + (size_t)i * D_INNER * D_STATE, D_skip + i * D_INNER,
            dtproj_W + (size_t)i * D_INNER * DT_RANK, dtproj_b + i * D_INNER, dts, yb);
        // out_proj + residual + LN (layers 0-2) / RMS (layer 3) fused
        if (i < N_LAYERS - 1)
            gemm_out_ln<false><<<T / 64, 256, 0, stream>>>(
                yb, wb_out + (size_t)i * D_MODEL * D_INNER, resid,
                ln_w + (i + 1) * D_MODEL, ln_b + (i + 1) * D_MODEL, hb);
        else
            gemm_out_ln<true><<<T / 64, 256, 0, stream>>>(
                yb, wb_out + (size_t)i * D_MODEL * D_INNER, resid,
                normf_w, normf_b, hb);
    }

    // head: (9600,256) x (300,256)^T -> (9600,300) f32
    gemm_mfma<64, 64, true, false><<<dim3(T / 64, 5), 256, 0, stream>>>(
        hb, wb_hd, out, CITY, D_MODEL);
}